// Round 11
// baseline (64.454 us; speedup 1.0000x reference)
//
#include <hip/hip_runtime.h>
#include <hip/hip_bf16.h>

// Problem constants (fixed by the reference)
#define NUM_WORDS 200000
#define EMBED 128
#define BATCH 16384
#define WIN 8
#define B_PER_BLK 8
#define GRID (BATCH / B_PER_BLK)   // 2048 blocks

typedef __attribute__((ext_vector_type(8))) short short8;   // 8 bf16 in 4 VGPRs
typedef __attribute__((ext_vector_type(4))) float f32x4;

#define LN_HALF (-0.69314718056f)

__device__ __forceinline__ short f2bf(float f) {
  unsigned u = __float_as_uint(f);
  u = u + 0x7FFFu + ((u >> 16) & 1u);   // round-to-nearest-even
  return (short)(u >> 16);
}

__device__ __forceinline__ float sp(float x) {   // stable softplus (for dots)
  return fmaxf(x, 0.f) + __logf(1.f + __expf(-fabsf(x)));
}

__device__ __forceinline__ f32x4 ntload4(const float* p) {  // non-temporal 16B
  return __builtin_nontemporal_load((const f32x4*)p);
}

// ---------------------------------------------------------------------------
// Pre-pass: pack B-fragments of A^T = lin_w[:, :128]^T (bf16, MFMA B layout)
// and cov_proj[c][j] = lin_b[j] + sum_k cov_w[c][k]*lin_w[j][128+k]  (f32)
// ---------------------------------------------------------------------------
__global__ void prep_kernel(const float* __restrict__ lin_w,
                            const float* __restrict__ lin_b,
                            const float* __restrict__ cov_w,
                            short* __restrict__ bpack,
                            float* __restrict__ covp) {
  int t = blockIdx.x * 256 + threadIdx.x;
  if (t < 16384) {
    int e  = t & 7;
    int l  = (t >> 3) & 63;
    int jt = (t >> 9) & 1;
    int kk = (t >> 10) & 3;
    int wv = (t >> 12) & 3;
    int j = wv * 32 + jt * 16 + (l & 15);        // B col (N)
    int k = kk * 32 + (l >> 4) * 8 + e;          // B row (K)
    bpack[t] = f2bf(lin_w[j * 256 + k]);         // B[k][n] = lin_w[j][k]
  } else if (t < 16384 + 1280) {
    int u = t - 16384;
    int c = u >> 7, j = u & 127;
    float s = lin_b[j];
    for (int k = 0; k < 128; ++k)
      s += cov_w[c * 128 + k] * lin_w[j * 256 + 128 + k];
    covp[u] = s;
  }
}

// ---------------------------------------------------------------------------
// Main kernel. Phase 1: MFMA matvec + per-b terms. Phase 2: 8 lanes per
// (b,w) row, line-exact mapping; ALL 32 gather float4s for BOTH window
// iterations issued back-to-back and pinned above compute with
// sched_barrier(0) -> it=1's 16 loads stay in flight under it=0's compute.
// launch_bounds(256,3): VGPR cap ~170, 12 waves/CU.
// ---------------------------------------------------------------------------
__global__ __launch_bounds__(256, 3) void main_kernel(
    const int* __restrict__ inputs, const int* __restrict__ outputs,
    const int* __restrict__ covars, const int* __restrict__ noise,
    const float* __restrict__ wtp,
    const float* __restrict__ eps_in, const float* __restrict__ eps_out,
    const float* __restrict__ in_w, const float* __restrict__ out_w,
    const float* __restrict__ in_rho_w, const float* __restrict__ out_rho_w,
    const short* __restrict__ bpack, const float* __restrict__ covp,
    double* __restrict__ parts) {
  __shared__ float w_s[B_PER_BLK][132];   // w_pre, then w_in (row stride pad)
  __shared__ float red_s[4];

  const int tid  = threadIdx.x;
  const int lane = tid & 63;
  const int wv   = tid >> 6;
  const int q    = lane >> 4;
  const int f16  = lane & 15;
  const int bbase = blockIdx.x * B_PER_BLK;
  const float wtv = wtp[0];

  // -------- resident B fragments (bf16 lin_w[:, :128]^T slice) --------------
  short8 bfrag[4][2];
  const int4* bp = (const int4*)bpack;
  #pragma unroll
  for (int kk = 0; kk < 4; ++kk) {
    #pragma unroll
    for (int jt = 0; jt < 2; ++jt) {
      int fi = (wv * 4 + kk) * 2 + jt;
      int4 v = bp[fi * 64 + lane];
      bfrag[kk][jt] = __builtin_bit_cast(short8, v);
    }
  }

  // -------- phase 1 MFMA: w_pre = mu_in @ lin_w[:, :128]^T ------------------
  int idxA = inputs[bbase + (f16 & (B_PER_BLK - 1))];
  f32x4 acc0 = {0.f, 0.f, 0.f, 0.f}, acc1 = {0.f, 0.f, 0.f, 0.f};
  #pragma unroll
  for (int kk = 0; kk < 4; ++kk) {
    const float* ap = in_w + (size_t)idxA * 128 + kk * 32 + q * 8;
    float4 a0 = *(const float4*)ap;
    float4 a1 = *(const float4*)(ap + 4);
    short8 af;
    af[0] = f2bf(a0.x); af[1] = f2bf(a0.y); af[2] = f2bf(a0.z); af[3] = f2bf(a0.w);
    af[4] = f2bf(a1.x); af[5] = f2bf(a1.y); af[6] = f2bf(a1.z); af[7] = f2bf(a1.w);
    acc0 = __builtin_amdgcn_mfma_f32_16x16x32_bf16(af, bfrag[kk][0], acc0, 0, 0, 0);
    acc1 = __builtin_amdgcn_mfma_f32_16x16x32_bf16(af, bfrag[kk][1], acc1, 0, 0, 0);
  }
  #pragma unroll
  for (int r = 0; r < 4; ++r) {
    int row = q * 4 + r;
    if (row < B_PER_BLK) {
      w_s[row][wv * 32 + f16]      = acc0[r];
      w_s[row][wv * 32 + 16 + f16] = acc1[r];
    }
  }
  __syncthreads();

  float accum = 0.f;

  // -------- phase 1 row pass: 32 threads per b, 4 elems each ----------------
  {
    const int b  = tid >> 5;
    const int j  = (tid & 31) * 4;
    const int gb = bbase + b;
    const int idx = inputs[gb];
    const int cov = covars[gb];

    float4 wp = *(const float4*)(&w_s[b][j]);
    float4 rh = *(const float4*)(in_rho_w + (size_t)idx * 128 + j);
    f32x4  ep = ntload4(eps_in + (size_t)gb * 128 + j);
    float4 cv = *(const float4*)(covp + cov * 128 + j);

    float rha[4] = {rh.x, rh.y, rh.z, rh.w};
    float epa[4] = {ep[0], ep[1], ep[2], ep[3]};
    float xa[4]  = {wp.x + cv.x, wp.y + cv.y, wp.z + cv.z, wp.w + cv.w};

    float wi4[4];
    float se2 = 0.f, sw2 = 0.f, ps = 1.f, pu = 1.f;
    #pragma unroll
    for (int e = 0; e < 4; ++e) {
      float es = __expf(rha[e]);          // rho in (-1,1): no overflow
      float s  = __logf(1.f + es);        // softplus
      float x  = fminf(fmaxf(xa[e], -15.f), 15.f);
      float e2 = __expf(2.f * x);
      float th = (e2 - 1.f) / (e2 + 1.f);
      float w  = th + s * epa[e];
      wi4[e] = w;
      float u  = __expf(-12.f * w * w);
      ps *= s; pu *= (1.f + u);
      se2 += epa[e] * epa[e];
      sw2 += w * w;
    }
    // publish w_in
    *(float4*)(&w_s[b][j]) = make_float4(wi4[0], wi4[1], wi4[2], wi4[3]);
    // post_in - prior_in (this thread's 4-elem slice); weight 8 windows * wt
    float t1 = -0.5f * se2 - __logf(ps) + 0.5f * sw2 - 4.f * LN_HALF - __logf(pu);
    accum = 8.f * wtv * t1;
  }
  __syncthreads();

  // -------- phase 2: both iterations' 32 gathers issued, pinned, computed ---
  {
    const int g  = tid >> 3;             // row group 0..31
    const int f8 = tid & 7;              // lane in group

    const int rlA = g,       rlB = 32 + g;
    const int bA  = rlA >> 3, bB  = rlB >> 3;      // wave-uniform
    const int rA  = (bbase + bA) * 8 + (rlA & 7);
    const int rB  = (bbase + bB) * 8 + (rlB & 7);
    const int oA  = outputs[rA], nzA = noise[rA];
    const int oB  = outputs[rB], nzB = noise[rB];

    const float* wrowA = out_w     + (size_t)oA  * 128;
    const float* rrowA = out_rho_w + (size_t)oA  * 128;
    const float* erowA = eps_out   + (size_t)rA  * 128;
    const float* nrowA = out_w     + (size_t)nzA * 128;
    const float* wrowB = out_w     + (size_t)oB  * 128;
    const float* rrowB = out_rho_w + (size_t)oB  * 128;
    const float* erowB = eps_out   + (size_t)rB  * 128;
    const float* nrowB = out_w     + (size_t)nzB * 128;

    // issue ALL 32 gather loads back-to-back (32 in flight per thread)
    f32x4 moA[4], roA[4], eoA[4], nvA[4];
    f32x4 moB[4], roB[4], eoB[4], nvB[4];
    #pragma unroll
    for (int c = 0; c < 4; ++c) {
      const int off = (c * 8 + f8) * 4;   // 8 lanes -> one full 128B line
      moA[c] = *(const f32x4*)(wrowA + off);
      roA[c] = *(const f32x4*)(rrowA + off);
      eoA[c] = ntload4(erowA + off);
      nvA[c] = *(const f32x4*)(nrowA + off);
    }
    #pragma unroll
    for (int c = 0; c < 4; ++c) {
      const int off = (c * 8 + f8) * 4;
      moB[c] = *(const f32x4*)(wrowB + off);
      roB[c] = *(const f32x4*)(rrowB + off);
      eoB[c] = ntload4(erowB + off);
      nvB[c] = *(const f32x4*)(nrowB + off);
    }
    // pin: loads stay above, compute below -> it=1 loads in flight during it=0
    __builtin_amdgcn_sched_barrier(0);

    #pragma unroll
    for (int it = 0; it < 2; ++it) {
      const f32x4* mo = it ? moB : moA;
      const f32x4* ro = it ? roB : roA;
      const f32x4* eo = it ? eoB : eoA;
      const f32x4* nv = it ? nvB : nvA;
      const int b2 = it ? bB : bA;

      float d1 = 0.f, d2 = 0.f, se2 = 0.f, sw2 = 0.f;
      float ps = 1.f, pu = 1.f;

      #pragma unroll
      for (int c = 0; c < 4; ++c) {
        const int off = (c * 8 + f8) * 4;
        float4 wi = *(const float4*)(&w_s[b2][off]);
        float moa[4] = {mo[c][0], mo[c][1], mo[c][2], mo[c][3]};
        float roa[4] = {ro[c][0], ro[c][1], ro[c][2], ro[c][3]};
        float eoa[4] = {eo[c][0], eo[c][1], eo[c][2], eo[c][3]};
        float nva[4] = {nv[c][0], nv[c][1], nv[c][2], nv[c][3]};
        float wia[4] = {wi.x, wi.y, wi.z, wi.w};

        #pragma unroll
        for (int e = 0; e < 4; ++e) {
          float es = __expf(roa[e]);       // rho in (-1,1)
          float s  = __logf(1.f + es);
          float wo = fmaf(s, eoa[e], moa[e]);
          float u  = __expf(-12.f * wo * wo);
          ps *= s;
          pu *= (1.f + u);
          se2 += eoa[e] * eoa[e];
          sw2 += wo * wo;
          d1  += wia[e] * wo;
          d2  += wia[e] * nva[e];
        }
      }
      // linear part: wt * (post_out - prior_out) slice (16 elems)
      float t2 = -0.5f * se2 - __logf(ps) + 0.5f * sw2 - 16.f * LN_HALF - __logf(pu);
      accum += wtv * t2;

      // full-row dots: reduce over the 8-lane group
      d1 += __shfl_xor(d1, 1, 64); d1 += __shfl_xor(d1, 2, 64); d1 += __shfl_xor(d1, 4, 64);
      d2 += __shfl_xor(d2, 1, 64); d2 += __shfl_xor(d2, 2, 64); d2 += __shfl_xor(d2, 4, 64);
      if (f8 == 0) accum += sp(-d1) + sp(d2);   // -log_target - log_sampled
    }
  }

  // -------- deterministic block reduction ----------------------------------
  #pragma unroll
  for (int m = 1; m <= 32; m <<= 1) accum += __shfl_xor(accum, m, 64);
  if (lane == 0) red_s[wv] = accum;
  __syncthreads();
  if (tid == 0) {
    double s = (double)red_s[0] + (double)red_s[1] + (double)red_s[2] + (double)red_s[3];
    parts[blockIdx.x] = s;
  }
}

// ---------------------------------------------------------------------------
// Final deterministic reduction: block partials -> mean
// ---------------------------------------------------------------------------
__global__ void fin_kernel(const double* __restrict__ parts, float* __restrict__ out) {
  __shared__ double s[256];
  const int tid = threadIdx.x;
  double a = 0.0;
  for (int i = tid; i < GRID; i += 256) a += parts[i];
  s[tid] = a;
  __syncthreads();
  for (int st = 128; st > 0; st >>= 1) {
    if (tid < st) s[tid] += s[tid + st];
    __syncthreads();
  }
  if (tid == 0) out[0] = (float)(s[0] / (double)(BATCH * WIN));
}

extern "C" void kernel_launch(void* const* d_in, const int* in_sizes, int n_in,
                              void* d_out, int out_size, void* d_ws, size_t ws_size,
                              hipStream_t stream) {
  const int*   inputs    = (const int*)d_in[0];
  const int*   outputs   = (const int*)d_in[1];
  const int*   covars    = (const int*)d_in[2];
  const int*   noise     = (const int*)d_in[3];
  const float* wt        = (const float*)d_in[4];
  const float* eps_in    = (const float*)d_in[5];
  const float* eps_out   = (const float*)d_in[6];
  const float* in_w      = (const float*)d_in[7];
  const float* out_w     = (const float*)d_in[8];
  const float* in_rho_w  = (const float*)d_in[9];
  const float* out_rho_w = (const float*)d_in[10];
  const float* cov_w     = (const float*)d_in[11];
  const float* lin_w     = (const float*)d_in[12];
  const float* lin_b     = (const float*)d_in[13];

  short*  bpack = (short*)d_ws;                            // 32768 B
  float*  covp  = (float*)((char*)d_ws + 32768);           // 5120 B
  double* parts = (double*)((char*)d_ws + 40960);          // 16384 B

  prep_kernel<<<69, 256, 0, stream>>>(lin_w, lin_b, cov_w, bpack, covp);
  main_kernel<<<GRID, 256, 0, stream>>>(inputs, outputs, covars, noise, wt,
                                        eps_in, eps_out, in_w, out_w,
                                        in_rho_w, out_rho_w, bpack, covp, parts);
  fin_kernel<<<1, 256, 0, stream>>>(parts, (float*)d_out);
}

// Round 12
// 62.190 us; speedup vs baseline: 1.0364x; 1.0364x over previous
//
#include <hip/hip_runtime.h>
#include <hip/hip_bf16.h>

// Problem constants (fixed by the reference)
#define NUM_WORDS 200000
#define EMBED 128
#define BATCH 16384
#define WIN 8
#define B_PER_BLK 8
#define GRID (BATCH / B_PER_BLK)   // 2048 blocks

typedef __attribute__((ext_vector_type(8))) short short8;   // 8 bf16 in 4 VGPRs
typedef __attribute__((ext_vector_type(4))) float f32x4;

#define LN_HALF (-0.69314718056f)

__device__ __forceinline__ short f2bf(float f) {
  unsigned u = __float_as_uint(f);
  u = u + 0x7FFFu + ((u >> 16) & 1u);   // round-to-nearest-even
  return (short)(u >> 16);
}

__device__ __forceinline__ float sp(float x) {   // stable softplus (for dots)
  return fmaxf(x, 0.f) + __logf(1.f + __expf(-fabsf(x)));
}

__device__ __forceinline__ f32x4 ntload4(const float* p) {  // non-temporal 16B
  return __builtin_nontemporal_load((const f32x4*)p);
}

// ---------------------------------------------------------------------------
// Pre-pass: pack B-fragments of A^T = lin_w[:, :128]^T (bf16, MFMA B layout)
// and cov_proj[c][j] = lin_b[j] + sum_k cov_w[c][k]*lin_w[j][128+k]  (f32)
// ---------------------------------------------------------------------------
__global__ void prep_kernel(const float* __restrict__ lin_w,
                            const float* __restrict__ lin_b,
                            const float* __restrict__ cov_w,
                            short* __restrict__ bpack,
                            float* __restrict__ covp) {
  int t = blockIdx.x * 256 + threadIdx.x;
  if (t < 16384) {
    int e  = t & 7;
    int l  = (t >> 3) & 63;
    int jt = (t >> 9) & 1;
    int kk = (t >> 10) & 3;
    int wv = (t >> 12) & 3;
    int j = wv * 32 + jt * 16 + (l & 15);        // B col (N)
    int k = kk * 32 + (l >> 4) * 8 + e;          // B row (K)
    bpack[t] = f2bf(lin_w[j * 256 + k]);         // B[k][n] = lin_w[j][k]
  } else if (t < 16384 + 1280) {
    int u = t - 16384;
    int c = u >> 7, j = u & 127;
    float s = lin_b[j];
    for (int k = 0; k < 128; ++k)
      s += cov_w[c * 128 + k] * lin_w[j * 256 + 128 + k];
    covp[u] = s;
  }
}

// ---------------------------------------------------------------------------
// Main kernel (measured-best R10 structure). Phase 1: MFMA matvec + per-b
// terms. Phase 2: 8 lanes per (b,w) row, line-exact mapping, register
// preload, prefetched indices. Streamed-once eps arrays use non-temporal
// loads so L2/L3 capacity favors the reused out_w / out_rho_w tables.
// ---------------------------------------------------------------------------
__global__ __launch_bounds__(256, 5) void main_kernel(
    const int* __restrict__ inputs, const int* __restrict__ outputs,
    const int* __restrict__ covars, const int* __restrict__ noise,
    const float* __restrict__ wtp,
    const float* __restrict__ eps_in, const float* __restrict__ eps_out,
    const float* __restrict__ in_w, const float* __restrict__ out_w,
    const float* __restrict__ in_rho_w, const float* __restrict__ out_rho_w,
    const short* __restrict__ bpack, const float* __restrict__ covp,
    double* __restrict__ parts) {
  __shared__ float w_s[B_PER_BLK][132];   // w_pre, then w_in (row stride pad)
  __shared__ float red_s[4];

  const int tid  = threadIdx.x;
  const int lane = tid & 63;
  const int wv   = tid >> 6;
  const int q    = lane >> 4;
  const int f16  = lane & 15;
  const int bbase = blockIdx.x * B_PER_BLK;
  const float wtv = wtp[0];

  // -------- resident B fragments (bf16 lin_w[:, :128]^T slice) --------------
  short8 bfrag[4][2];
  const int4* bp = (const int4*)bpack;
  #pragma unroll
  for (int kk = 0; kk < 4; ++kk) {
    #pragma unroll
    for (int jt = 0; jt < 2; ++jt) {
      int fi = (wv * 4 + kk) * 2 + jt;
      int4 v = bp[fi * 64 + lane];
      bfrag[kk][jt] = __builtin_bit_cast(short8, v);
    }
  }

  // -------- phase 1 MFMA: w_pre = mu_in @ lin_w[:, :128]^T ------------------
  int idxA = inputs[bbase + (f16 & (B_PER_BLK - 1))];
  f32x4 acc0 = {0.f, 0.f, 0.f, 0.f}, acc1 = {0.f, 0.f, 0.f, 0.f};
  #pragma unroll
  for (int kk = 0; kk < 4; ++kk) {
    const float* ap = in_w + (size_t)idxA * 128 + kk * 32 + q * 8;
    float4 a0 = *(const float4*)ap;
    float4 a1 = *(const float4*)(ap + 4);
    short8 af;
    af[0] = f2bf(a0.x); af[1] = f2bf(a0.y); af[2] = f2bf(a0.z); af[3] = f2bf(a0.w);
    af[4] = f2bf(a1.x); af[5] = f2bf(a1.y); af[6] = f2bf(a1.z); af[7] = f2bf(a1.w);
    acc0 = __builtin_amdgcn_mfma_f32_16x16x32_bf16(af, bfrag[kk][0], acc0, 0, 0, 0);
    acc1 = __builtin_amdgcn_mfma_f32_16x16x32_bf16(af, bfrag[kk][1], acc1, 0, 0, 0);
  }
  #pragma unroll
  for (int r = 0; r < 4; ++r) {
    int row = q * 4 + r;
    if (row < B_PER_BLK) {
      w_s[row][wv * 32 + f16]      = acc0[r];
      w_s[row][wv * 32 + 16 + f16] = acc1[r];
    }
  }
  __syncthreads();

  float accum = 0.f;

  // -------- phase 1 row pass: 32 threads per b, 4 elems each ----------------
  {
    const int b  = tid >> 5;
    const int j  = (tid & 31) * 4;
    const int gb = bbase + b;
    const int idx = inputs[gb];
    const int cov = covars[gb];

    float4 wp = *(const float4*)(&w_s[b][j]);
    float4 rh = *(const float4*)(in_rho_w + (size_t)idx * 128 + j);
    f32x4  ep = ntload4(eps_in + (size_t)gb * 128 + j);
    float4 cv = *(const float4*)(covp + cov * 128 + j);

    float rha[4] = {rh.x, rh.y, rh.z, rh.w};
    float epa[4] = {ep[0], ep[1], ep[2], ep[3]};
    float xa[4]  = {wp.x + cv.x, wp.y + cv.y, wp.z + cv.z, wp.w + cv.w};

    float wi4[4];
    float se2 = 0.f, sw2 = 0.f, ps = 1.f, pu = 1.f;
    #pragma unroll
    for (int e = 0; e < 4; ++e) {
      float es = __expf(rha[e]);          // rho in (-1,1): no overflow
      float s  = __logf(1.f + es);        // softplus
      float x  = fminf(fmaxf(xa[e], -15.f), 15.f);
      float e2 = __expf(2.f * x);
      float th = (e2 - 1.f) / (e2 + 1.f);
      float w  = th + s * epa[e];
      wi4[e] = w;
      float u  = __expf(-12.f * w * w);
      ps *= s; pu *= (1.f + u);
      se2 += epa[e] * epa[e];
      sw2 += w * w;
    }
    // publish w_in
    *(float4*)(&w_s[b][j]) = make_float4(wi4[0], wi4[1], wi4[2], wi4[3]);
    // post_in - prior_in (this thread's 4-elem slice); weight 8 windows * wt
    float t1 = -0.5f * se2 - __logf(ps) + 0.5f * sw2 - 4.f * LN_HALF - __logf(pu);
    accum = 8.f * wtv * t1;
  }
  __syncthreads();

  // -------- phase 2: 8 lanes per row, full register preload per row ---------
  {
    const int g  = tid >> 3;             // row group 0..31
    const int f8 = tid & 7;              // lane in group

    // prefetch both iterations' indices up front
    const int rlA = g,       rlB = 32 + g;
    const int bA  = rlA >> 3, bB  = rlB >> 3;      // wave-uniform
    const int rA  = (bbase + bA) * 8 + (rlA & 7);
    const int rB  = (bbase + bB) * 8 + (rlB & 7);
    const int oA  = outputs[rA], nzA = noise[rA];
    const int oB  = outputs[rB], nzB = noise[rB];

    #pragma unroll
    for (int it = 0; it < 2; ++it) {
      const int o  = it ? oB : oA;
      const int nz = it ? nzB : nzA;
      const int r  = it ? rB : rA;
      const int b2 = it ? bB : bA;
      const float* wrow = out_w     + (size_t)o  * 128;
      const float* rrow = out_rho_w + (size_t)o  * 128;
      const float* erow = eps_out   + (size_t)r  * 128;
      const float* nrow = out_w     + (size_t)nz * 128;

      // issue ALL 16 gather loads before any compute
      float4 mo[4], ro[4], nv[4];
      f32x4  eo[4];
      #pragma unroll
      for (int c = 0; c < 4; ++c) {
        const int off = (c * 8 + f8) * 4;   // 8 lanes -> one full 128B line
        mo[c] = *(const float4*)(wrow + off);
        ro[c] = *(const float4*)(rrow + off);
        eo[c] = ntload4(erow + off);
        nv[c] = *(const float4*)(nrow + off);
      }

      float d1 = 0.f, d2 = 0.f, se2 = 0.f, sw2 = 0.f;
      float ps = 1.f, pu = 1.f;

      #pragma unroll
      for (int c = 0; c < 4; ++c) {
        const int off = (c * 8 + f8) * 4;
        float4 wi = *(const float4*)(&w_s[b2][off]);
        float moa[4] = {mo[c].x, mo[c].y, mo[c].z, mo[c].w};
        float roa[4] = {ro[c].x, ro[c].y, ro[c].z, ro[c].w};
        float eoa[4] = {eo[c][0], eo[c][1], eo[c][2], eo[c][3]};
        float nva[4] = {nv[c].x, nv[c].y, nv[c].z, nv[c].w};
        float wia[4] = {wi.x, wi.y, wi.z, wi.w};

        #pragma unroll
        for (int e = 0; e < 4; ++e) {
          float es = __expf(roa[e]);       // rho in (-1,1)
          float s  = __logf(1.f + es);
          float wo = fmaf(s, eoa[e], moa[e]);
          float u  = __expf(-12.f * wo * wo);
          ps *= s;
          pu *= (1.f + u);
          se2 += eoa[e] * eoa[e];
          sw2 += wo * wo;
          d1  += wia[e] * wo;
          d2  += wia[e] * nva[e];
        }
      }
      // linear part: wt * (post_out - prior_out) slice (16 elems)
      float t2 = -0.5f * se2 - __logf(ps) + 0.5f * sw2 - 16.f * LN_HALF - __logf(pu);
      accum += wtv * t2;

      // full-row dots: reduce over the 8-lane group
      d1 += __shfl_xor(d1, 1, 64); d1 += __shfl_xor(d1, 2, 64); d1 += __shfl_xor(d1, 4, 64);
      d2 += __shfl_xor(d2, 1, 64); d2 += __shfl_xor(d2, 2, 64); d2 += __shfl_xor(d2, 4, 64);
      if (f8 == 0) accum += sp(-d1) + sp(d2);   // -log_target - log_sampled
    }
  }

  // -------- deterministic block reduction ----------------------------------
  #pragma unroll
  for (int m = 1; m <= 32; m <<= 1) accum += __shfl_xor(accum, m, 64);
  if (lane == 0) red_s[wv] = accum;
  __syncthreads();
  if (tid == 0) {
    double s = (double)red_s[0] + (double)red_s[1] + (double)red_s[2] + (double)red_s[3];
    parts[blockIdx.x] = s;
  }
}

// ---------------------------------------------------------------------------
// Final deterministic reduction: block partials -> mean
// ---------------------------------------------------------------------------
__global__ void fin_kernel(const double* __restrict__ parts, float* __restrict__ out) {
  __shared__ double s[256];
  const int tid = threadIdx.x;
  double a = 0.0;
  for (int i = tid; i < GRID; i += 256) a += parts[i];
  s[tid] = a;
  __syncthreads();
  for (int st = 128; st > 0; st >>= 1) {
    if (tid < st) s[tid] += s[tid + st];
    __syncthreads();
  }
  if (tid == 0) out[0] = (float)(s[0] / (double)(BATCH * WIN));
}

extern "C" void kernel_launch(void* const* d_in, const int* in_sizes, int n_in,
                              void* d_out, int out_size, void* d_ws, size_t ws_size,
                              hipStream_t stream) {
  const int*   inputs    = (const int*)d_in[0];
  const int*   outputs   = (const int*)d_in[1];
  const int*   covars    = (const int*)d_in[2];
  const int*   noise     = (const int*)d_in[3];
  const float* wt        = (const float*)d_in[4];
  const float* eps_in    = (const float*)d_in[5];
  const float* eps_out   = (const float*)d_in[6];
  const float* in_w      = (const float*)d_in[7];
  const float* out_w     = (const float*)d_in[8];
  const float* in_rho_w  = (const float*)d_in[9];
  const float* out_rho_w = (const float*)d_in[10];
  const float* cov_w     = (const float*)d_in[11];
  const float* lin_w     = (const float*)d_in[12];
  const float* lin_b     = (const float*)d_in[13];

  short*  bpack = (short*)d_ws;                            // 32768 B
  float*  covp  = (float*)((char*)d_ws + 32768);           // 5120 B
  double* parts = (double*)((char*)d_ws + 40960);          // 16384 B

  prep_kernel<<<69, 256, 0, stream>>>(lin_w, lin_b, cov_w, bpack, covp);
  main_kernel<<<GRID, 256, 0, stream>>>(inputs, outputs, covars, noise, wt,
                                        eps_in, eps_out, in_w, out_w,
                                        in_rho_w, out_rho_w, bpack, covp, parts);
  fin_kernel<<<1, 256, 0, stream>>>(parts, (float*)d_out);
}